// Round 1
// baseline (443.510 us; speedup 1.0000x reference)
//
#include <hip/hip_runtime.h>

#define IN_DIM 512
#define EPS 1e-5f
// 1/sqrt(512)
#define SIM_SCALE 0.04419417382415922f

__device__ __forceinline__ float wave_reduce_sum(float v) {
    #pragma unroll
    for (int m = 1; m < 64; m <<= 1) v += __shfl_xor(v, m, 64);
    return v;
}

__device__ __forceinline__ float wave_reduce_max(float v) {
    #pragma unroll
    for (int m = 1; m < 64; m <<= 1) v = fmaxf(v, __shfl_xor(v, m, 64));
    return v;
}

// Per wave: one row. Lane holds elements [4*lane .. 4*lane+3] and [256+4*lane .. 256+4*lane+3].
// out_x = LN(softmax(x*s1)*x + x, g1, b1); out_y = LN(softmax(x*s2)*y + y, g2, b2)
// where s1 = (y . W1)/sqrt(d), s2 = (y . W2)/sqrt(d).

__device__ __forceinline__ void softmax_resid_ln_store(
    const float4& sa, const float4& sb,      // softmax input: s * x (8 vals)
    const float4& ba, const float4& bb,      // residual base (x or y)
    const float4& ga, const float4& gb,      // gamma
    const float4& ta, const float4& tb,      // beta
    float4* __restrict__ dst, int lane)
{
    // --- softmax over 512 ---
    float m = fmaxf(fmaxf(fmaxf(sa.x, sa.y), fmaxf(sa.z, sa.w)),
                    fmaxf(fmaxf(sb.x, sb.y), fmaxf(sb.z, sb.w)));
    m = wave_reduce_max(m);
    float e0 = expf(sa.x - m), e1 = expf(sa.y - m), e2 = expf(sa.z - m), e3 = expf(sa.w - m);
    float e4 = expf(sb.x - m), e5 = expf(sb.y - m), e6 = expf(sb.z - m), e7 = expf(sb.w - m);
    float denom = wave_reduce_sum(e0 + e1 + e2 + e3 + e4 + e5 + e6 + e7);
    float inv = 1.0f / denom;

    // --- o = p * base + base ---
    float o0 = fmaf(e0 * inv, ba.x, ba.x);
    float o1 = fmaf(e1 * inv, ba.y, ba.y);
    float o2 = fmaf(e2 * inv, ba.z, ba.z);
    float o3 = fmaf(e3 * inv, ba.w, ba.w);
    float o4 = fmaf(e4 * inv, bb.x, bb.x);
    float o5 = fmaf(e5 * inv, bb.y, bb.y);
    float o6 = fmaf(e6 * inv, bb.z, bb.z);
    float o7 = fmaf(e7 * inv, bb.w, bb.w);

    // --- layernorm ---
    float s  = o0 + o1 + o2 + o3 + o4 + o5 + o6 + o7;
    float sq = o0*o0 + o1*o1 + o2*o2 + o3*o3 + o4*o4 + o5*o5 + o6*o6 + o7*o7;
    s  = wave_reduce_sum(s);
    sq = wave_reduce_sum(sq);
    const float mu  = s * (1.0f / IN_DIM);
    const float var = sq * (1.0f / IN_DIM) - mu * mu;
    const float r   = rsqrtf(var + EPS);

    float4 ra, rb;
    ra.x = fmaf((o0 - mu) * r, ga.x, ta.x);
    ra.y = fmaf((o1 - mu) * r, ga.y, ta.y);
    ra.z = fmaf((o2 - mu) * r, ga.z, ta.z);
    ra.w = fmaf((o3 - mu) * r, ga.w, ta.w);
    rb.x = fmaf((o4 - mu) * r, gb.x, tb.x);
    rb.y = fmaf((o5 - mu) * r, gb.y, tb.y);
    rb.z = fmaf((o6 - mu) * r, gb.z, tb.z);
    rb.w = fmaf((o7 - mu) * r, gb.w, tb.w);
    dst[lane]      = ra;
    dst[lane + 64] = rb;
}

__global__ __launch_bounds__(256, 4) void simblock_kernel(
    const float* __restrict__ x, const float* __restrict__ y,
    const float* __restrict__ W1, const float* __restrict__ W2,
    const float* __restrict__ g1, const float* __restrict__ b1,
    const float* __restrict__ g2, const float* __restrict__ b2,
    float* __restrict__ out, int B)
{
    const int lane = threadIdx.x & 63;
    const int wave = threadIdx.x >> 6;
    const int row  = (blockIdx.x << 2) + wave;
    if (row >= B) return;

    const float4* x4  = (const float4*)(x + (size_t)row * IN_DIM);
    const float4* y4  = (const float4*)(y + (size_t)row * IN_DIM);
    const float4* w14 = (const float4*)W1;
    const float4* w24 = (const float4*)W2;

    const float4 xa = x4[lane], xb = x4[lane + 64];
    const float4 ya = y4[lane], yb = y4[lane + 64];
    const float4 wa1 = w14[lane], wb1 = w14[lane + 64];
    const float4 wa2 = w24[lane], wb2 = w24[lane + 64];

    // s1 = (y . W1) * scale; s2 = (y . W2) * scale  — reduce both together
    float d1 = ya.x*wa1.x + ya.y*wa1.y + ya.z*wa1.z + ya.w*wa1.w
             + yb.x*wb1.x + yb.y*wb1.y + yb.z*wb1.z + yb.w*wb1.w;
    float d2 = ya.x*wa2.x + ya.y*wa2.y + ya.z*wa2.z + ya.w*wa2.w
             + yb.x*wb2.x + yb.y*wb2.y + yb.z*wb2.z + yb.w*wb2.w;
    const float s1 = wave_reduce_sum(d1) * SIM_SCALE;
    const float s2 = wave_reduce_sum(d2) * SIM_SCALE;

    const float4* g14 = (const float4*)g1;
    const float4* b14 = (const float4*)b1;
    const float4* g24 = (const float4*)g2;
    const float4* b24 = (const float4*)b2;

    // out_x
    {
        float4 sa, sb;
        sa.x = xa.x * s1; sa.y = xa.y * s1; sa.z = xa.z * s1; sa.w = xa.w * s1;
        sb.x = xb.x * s1; sb.y = xb.y * s1; sb.z = xb.z * s1; sb.w = xb.w * s1;
        float4* dst = (float4*)(out + (size_t)row * IN_DIM);
        softmax_resid_ln_store(sa, sb, xa, xb,
                               g14[lane], g14[lane + 64],
                               b14[lane], b14[lane + 64], dst, lane);
    }
    // out_y
    {
        float4 sa, sb;
        sa.x = xa.x * s2; sa.y = xa.y * s2; sa.z = xa.z * s2; sa.w = xa.w * s2;
        sb.x = xb.x * s2; sb.y = xb.y * s2; sb.z = xb.z * s2; sb.w = xb.w * s2;
        float4* dst = (float4*)(out + (size_t)(B + row) * IN_DIM);
        softmax_resid_ln_store(sa, sb, ya, yb,
                               g24[lane], g24[lane + 64],
                               b24[lane], b24[lane + 64], dst, lane);
    }
}

extern "C" void kernel_launch(void* const* d_in, const int* in_sizes, int n_in,
                              void* d_out, int out_size, void* d_ws, size_t ws_size,
                              hipStream_t stream) {
    const float* x  = (const float*)d_in[0];
    const float* y  = (const float*)d_in[1];
    const float* W1 = (const float*)d_in[2];
    const float* W2 = (const float*)d_in[3];
    const float* g1 = (const float*)d_in[4];
    const float* b1 = (const float*)d_in[5];
    const float* g2 = (const float*)d_in[6];
    const float* b2 = (const float*)d_in[7];
    float* out = (float*)d_out;

    const int B = in_sizes[0] / IN_DIM;
    const int rows_per_block = 4;  // 4 waves x 1 row
    const int grid = (B + rows_per_block - 1) / rows_per_block;
    simblock_kernel<<<grid, 256, 0, stream>>>(x, y, W1, W2, g1, b1, g2, b2, out, B);
}